// Round 5
// baseline (304.927 us; speedup 1.0000x reference)
//
#include <hip/hip_runtime.h>
#include <hip/hip_cooperative_groups.h>

namespace cg = cooperative_groups;

#define NN   30000
#define NCTX 32
#define FIN  256
#define HID  128

typedef short short8 __attribute__((ext_vector_type(8)));
typedef float f32x4  __attribute__((ext_vector_type(4)));

__device__ __forceinline__ unsigned short f2b(float x) {
    union { float f; unsigned u; } v; v.f = x;
    unsigned r = v.u + 0x7FFFu + ((v.u >> 16) & 1u);   // RTNE
    return (unsigned short)(r >> 16);
}
__device__ __forceinline__ float b2f(unsigned short u) {
    union { unsigned u; float f; } v; v.u = ((unsigned)u) << 16;
    return v.f;
}

// One kernel: phase0 pack W_j (split bf16 hi/lo) + vi ; phase1 MFMA gemm
// (Wh = h_i @ W_j, fused score dots) ; phase2 softmax + gather-aggregate.
__global__ __launch_bounds__(256, 4) void k_fused(
        const float* __restrict__ hin, const int* __restrict__ ctxp,
        const float* __restrict__ Wi,  const float* __restrict__ Wj,
        const float* __restrict__ aw,  const float* __restrict__ ab,
        float* __restrict__ out,
        unsigned short* __restrict__ Wh, float* __restrict__ sib,
        float* __restrict__ sjv, float* __restrict__ vi,
        short8* __restrict__ whi, short8* __restrict__ wlo) {
    cg::grid_group grid = cg::this_grid();
    const int tid   = threadIdx.x;
    const int bid   = blockIdx.x;
    const int l     = tid & 63;
    const int gwave = bid * 4 + (tid >> 6);
    const int nwave = gridDim.x * 4;

    // ---------------- phase 0: pack ----------------
    if (bid < 16) {
        const int u = bid * 256 + tid;      // 4096 units = 64 b-blocks x 64 lanes
        const int b = u >> 6, ll = u & 63;
        const int s = b >> 3, t = b & 7;
        const int kbase = s * 32 + (ll >> 4) * 8;
        const int c = t * 16 + (ll & 15);
        short8 hi, lo;
        #pragma unroll
        for (int j = 0; j < 8; ++j) {
            const float w = Wj[(long)(kbase + j) * HID + c];
            const unsigned short h = f2b(w);
            hi[j] = (short)h;
            lo[j] = (short)f2b(w - b2f(h));
        }
        whi[b * 64 + ll] = hi;
        wlo[b * 64 + ll] = lo;
    } else if (bid == 16) {
        const int f = tid;                  // 256 threads = 256 features
        float s = 0.f;
        #pragma unroll 8
        for (int h = 0; h < HID; ++h) s += Wi[f * HID + h] * aw[h];
        vi[f] = s;
    }
    __threadfence();
    grid.sync();
    __threadfence();

    // ---------------- phase 1: gemm ----------------
    if (gwave < NN / 16) {
        const long rowbase = (long)gwave * 16;
        const int r  = l & 15;
        const int kg = l >> 4;
        const float* hrow = hin + (rowbase + r) * FIN + kg * 8;
        const float* vip  = vi + kg * 8;

        f32x4 acc[8];
        #pragma unroll
        for (int t = 0; t < 8; ++t) acc[t] = (f32x4){0.f, 0.f, 0.f, 0.f};
        float si = 0.f;

        #pragma unroll 2
        for (int s = 0; s < 8; ++s) {
            const float4 ha = *(const float4*)(hrow + s * 32);
            const float4 hb = *(const float4*)(hrow + s * 32 + 4);
            const float4 va = *(const float4*)(vip + s * 32);
            const float4 vb = *(const float4*)(vip + s * 32 + 4);
            const float hv[8] = {ha.x, ha.y, ha.z, ha.w, hb.x, hb.y, hb.z, hb.w};
            const float vv[8] = {va.x, va.y, va.z, va.w, vb.x, vb.y, vb.z, vb.w};
            short8 ahi, alo;
            #pragma unroll
            for (int j = 0; j < 8; ++j) {
                si += hv[j] * vv[j];
                const unsigned short hb16 = f2b(hv[j]);
                ahi[j] = (short)hb16;
                alo[j] = (short)f2b(hv[j] - b2f(hb16));
            }
            #pragma unroll
            for (int t = 0; t < 8; ++t) {
                const short8 bh = whi[(s * 8 + t) * 64 + l];
                const short8 bl = wlo[(s * 8 + t) * 64 + l];
                acc[t] = __builtin_amdgcn_mfma_f32_16x16x32_bf16(ahi, bh, acc[t], 0, 0, 0);
                acc[t] = __builtin_amdgcn_mfma_f32_16x16x32_bf16(alo, bh, acc[t], 0, 0, 0);
                acc[t] = __builtin_amdgcn_mfma_f32_16x16x32_bf16(ahi, bl, acc[t], 0, 0, 0);
            }
        }

        si += __shfl_xor(si, 16);
        si += __shfl_xor(si, 32);
        if (l < 16) sib[rowbase + l] = si + ab[0];

        float aw2v[8];
        #pragma unroll
        for (int t = 0; t < 8; ++t) aw2v[t] = aw[HID + t * 16 + r];
        #pragma unroll
        for (int j = 0; j < 4; ++j) {
            float p = 0.f;
            #pragma unroll
            for (int t = 0; t < 8; ++t) p += acc[t][j] * aw2v[t];
            p += __shfl_xor(p, 1); p += __shfl_xor(p, 2);
            p += __shfl_xor(p, 4); p += __shfl_xor(p, 8);
            if (r == 0) sjv[rowbase + kg * 4 + j] = p;
        }

        #pragma unroll
        for (int j = 0; j < 4; ++j) {
            const long rr = rowbase + kg * 4 + j;
            #pragma unroll
            for (int t = 0; t < 8; ++t)
                Wh[rr * HID + t * 16 + r] = f2b(acc[t][j]);
        }
    }
    __threadfence();
    grid.sync();
    __threadfence();

    // ---------------- phase 2: attn ----------------
    const int q  = l >> 4;
    const int cl = l & 15;
    for (int n = gwave; n < NN; n += nwave) {
        const int c   = l & 31;
        const int idx = ctxp[(long)n * NCTX + c];
        const int icl = (idx >= 0) ? idx : 0;
        float s;
        if (idx >= 0) {
            s = sib[n] + sjv[icl];
            s = (s >= 0.f) ? s : 0.2f * s;
        } else {
            s = -9e15f;
        }
        float mx = s;
        #pragma unroll
        for (int m = 16; m >= 1; m >>= 1) mx = fmaxf(mx, __shfl_xor(mx, m));
        const float e = __expf(s - mx);
        float sum = e;
        #pragma unroll
        for (int m = 16; m >= 1; m >>= 1) sum += __shfl_xor(sum, m);
        const float at = (idx >= 0) ? e / sum : 0.f;

        float a0 = 0.f, a1 = 0.f, a2 = 0.f, a3 = 0.f,
              a4 = 0.f, a5 = 0.f, a6 = 0.f, a7 = 0.f;
        #pragma unroll
        for (int it = 0; it < 8; ++it) {
            const int   src = it * 4 + q;
            const float w   = __shfl(at, src);
            const int   ic  = __shfl(icl, src);
            const uint4 pv  = *(const uint4*)(Wh + (long)ic * HID + cl * 8);
            a0 += w * b2f((unsigned short)(pv.x & 0xFFFFu));
            a1 += w * b2f((unsigned short)(pv.x >> 16));
            a2 += w * b2f((unsigned short)(pv.y & 0xFFFFu));
            a3 += w * b2f((unsigned short)(pv.y >> 16));
            a4 += w * b2f((unsigned short)(pv.z & 0xFFFFu));
            a5 += w * b2f((unsigned short)(pv.z >> 16));
            a6 += w * b2f((unsigned short)(pv.w & 0xFFFFu));
            a7 += w * b2f((unsigned short)(pv.w >> 16));
        }
        #pragma unroll
        for (int m = 16; m <= 32; m <<= 1) {
            a0 += __shfl_xor(a0, m); a1 += __shfl_xor(a1, m);
            a2 += __shfl_xor(a2, m); a3 += __shfl_xor(a3, m);
            a4 += __shfl_xor(a4, m); a5 += __shfl_xor(a5, m);
            a6 += __shfl_xor(a6, m); a7 += __shfl_xor(a7, m);
        }
        if (l < 16) {
            float4* op = (float4*)(out + (long)n * HID + cl * 8);
            op[0] = (float4){a0, a1, a2, a3};
            op[1] = (float4){a4, a5, a6, a7};
        }
    }
}

extern "C" void kernel_launch(void* const* d_in, const int* in_sizes, int n_in,
                              void* d_out, int out_size, void* d_ws, size_t ws_size,
                              hipStream_t stream) {
    const float* h_i = (const float*)d_in[0];
    const int*   ctx = (const int*)d_in[1];
    const float* W_i = (const float*)d_in[2];
    const float* W_j = (const float*)d_in[3];
    const float* a_w = (const float*)d_in[4];
    const float* a_b = (const float*)d_in[5];
    float* out = (float*)d_out;

    char* ws = (char*)d_ws;
    unsigned short* Wh = (unsigned short*)ws;             // N*H bf16 = 7,680,000 B
    float* sib = (float*)(ws + 7680000);                  // N f32
    float* sjv = (float*)(ws + 7800000);                  // N f32
    float* vi  = (float*)(ws + 7920000);                  // 256 f32
    short8* whi = (short8*)(ws + 7921024);                // 64 KB
    short8* wlo = (short8*)(ws + 7986560);                // 64 KB

    int maxb = 0;
    hipOccupancyMaxActiveBlocksPerMultiprocessor(&maxb, k_fused, 256, 0);
    if (maxb < 1) maxb = 1;
    if (maxb > 4) maxb = 4;
    int nblk = 256 * maxb;          // 256 CUs; guaranteed co-resident

    void* args[] = {(void*)&h_i, (void*)&ctx, (void*)&W_i, (void*)&W_j,
                    (void*)&a_w, (void*)&a_b, (void*)&out, (void*)&Wh,
                    (void*)&sib, (void*)&sjv, (void*)&vi, (void*)&whi,
                    (void*)&wlo};
    hipLaunchCooperativeKernel(k_fused, dim3(nblk), dim3(256), args, 0, stream);
}

// Round 6
// 62.087 us; speedup vs baseline: 4.9113x; 4.9113x over previous
//
#include <hip/hip_runtime.h>

#define NN   30000
#define NCTX 32
#define FIN  256
#define HID  128

typedef short short8 __attribute__((ext_vector_type(8)));
typedef float f32x4  __attribute__((ext_vector_type(4)));

__device__ __forceinline__ unsigned short f2b(float x) {   // RTNE
    union { float f; unsigned u; } v; v.f = x;
    unsigned r = v.u + 0x7FFFu + ((v.u >> 16) & 1u);
    return (unsigned short)(r >> 16);
}
__device__ __forceinline__ unsigned short f2b_trunc(float x) {
    union { float f; unsigned u; } v; v.f = x;
    return (unsigned short)(v.u >> 16);
}
__device__ __forceinline__ float b2f(unsigned short u) {
    union { unsigned u; float f; } v; v.u = ((unsigned)u) << 16;
    return v.f;
}

// Pack W_j into MFMA B-fragment order (split bf16 hi/lo); block 64 computes
// vi[f] = sum_h W_i[f][h]*a_w[h].
__global__ __launch_bounds__(64) void k_pack(const float* __restrict__ Wj,
                                             const float* __restrict__ Wi,
                                             const float* __restrict__ aw,
                                             short8* __restrict__ whi,
                                             short8* __restrict__ wlo,
                                             float* __restrict__ vi) {
    const int b = blockIdx.x;
    const int l = threadIdx.x;
    if (b == 64) {
        #pragma unroll
        for (int i = 0; i < 4; ++i) {
            const int f = l * 4 + i;
            float s = 0.f;
            #pragma unroll 8
            for (int h = 0; h < HID; ++h) s += Wi[f * HID + h] * aw[h];
            vi[f] = s;
        }
        return;
    }
    const int s = b >> 3, t = b & 7;
    const int kbase = s * 32 + (l >> 4) * 8;
    const int c = t * 16 + (l & 15);
    short8 hi, lo;
    #pragma unroll
    for (int j = 0; j < 8; ++j) {
        const float w = Wj[(long)(kbase + j) * HID + c];
        const unsigned short h = f2b_trunc(w);
        hi[j] = (short)h;
        lo[j] = (short)f2b(w - b2f(h));
    }
    whi[b * 64 + l] = hi;
    wlo[b * 64 + l] = lo;
}

// Fused: Wh = h_i @ W_j (MFMA, split-bf16), si = h_i.vi + ab, sj = Wh.a_w[128:]
// All 16 weight-fragment loads of an s-iter are issued into registers BEFORE
// the MFMA cluster: one L2 latency per s-iter, not 16.
__global__ __launch_bounds__(256) void k_gemm(const float* __restrict__ hin,
                                              const short8* __restrict__ whi,
                                              const short8* __restrict__ wlo,
                                              const float* __restrict__ vi,
                                              const float* __restrict__ aw,
                                              const float* __restrict__ ab,
                                              unsigned short* __restrict__ Wh,
                                              float* __restrict__ sib,
                                              float* __restrict__ sjv) {
    const int tid  = threadIdx.x;
    const int l    = tid & 63;
    const int wave = blockIdx.x * 4 + (tid >> 6);
    if (wave >= NN / 16) return;
    const long rowbase = (long)wave * 16;
    const int r  = l & 15;    // A row / D col-within-tile
    const int kg = l >> 4;    // k-group

    const float* hrow = hin + (rowbase + r) * FIN + kg * 8;
    const float* vip  = vi + kg * 8;

    f32x4 acc[8];
    #pragma unroll
    for (int t = 0; t < 8; ++t) acc[t] = (f32x4){0.f, 0.f, 0.f, 0.f};
    float si = 0.f;

    #pragma unroll
    for (int s = 0; s < 8; ++s) {
        // ---- issue all independent loads first (weights + h) ----
        short8 BH[8], BL[8];
        #pragma unroll
        for (int t = 0; t < 8; ++t) {
            BH[t] = whi[(s * 8 + t) * 64 + l];
            BL[t] = wlo[(s * 8 + t) * 64 + l];
        }
        const float4 ha = *(const float4*)(hrow + s * 32);
        const float4 hb = *(const float4*)(hrow + s * 32 + 4);
        const float4 va = *(const float4*)(vip + s * 32);
        const float4 vb = *(const float4*)(vip + s * 32 + 4);
        const float hv[8] = {ha.x, ha.y, ha.z, ha.w, hb.x, hb.y, hb.z, hb.w};
        const float vv[8] = {va.x, va.y, va.z, va.w, vb.x, vb.y, vb.z, vb.w};
        short8 ahi, alo;
        #pragma unroll
        for (int j = 0; j < 8; ++j) {
            si += hv[j] * vv[j];
            const unsigned short hb16 = f2b_trunc(hv[j]);   // 1-op truncation
            ahi[j] = (short)hb16;
            alo[j] = (short)f2b(hv[j] - b2f(hb16));         // RTNE residual
        }
        #pragma unroll
        for (int t = 0; t < 8; ++t) {
            acc[t] = __builtin_amdgcn_mfma_f32_16x16x32_bf16(ahi, BH[t], acc[t], 0, 0, 0);
            acc[t] = __builtin_amdgcn_mfma_f32_16x16x32_bf16(alo, BH[t], acc[t], 0, 0, 0);
            acc[t] = __builtin_amdgcn_mfma_f32_16x16x32_bf16(ahi, BL[t], acc[t], 0, 0, 0);
        }
    }

    si += __shfl_xor(si, 16);
    si += __shfl_xor(si, 32);
    if (l < 16) sib[rowbase + l] = si + ab[0];

    float aw2v[8];
    #pragma unroll
    for (int t = 0; t < 8; ++t) aw2v[t] = aw[HID + t * 16 + r];
    #pragma unroll
    for (int j = 0; j < 4; ++j) {
        float p = 0.f;
        #pragma unroll
        for (int t = 0; t < 8; ++t) p += acc[t][j] * aw2v[t];
        p += __shfl_xor(p, 1); p += __shfl_xor(p, 2);
        p += __shfl_xor(p, 4); p += __shfl_xor(p, 8);
        if (r == 0) sjv[rowbase + kg * 4 + j] = p;
    }

    #pragma unroll
    for (int j = 0; j < 4; ++j) {
        const long rr = rowbase + kg * 4 + j;
        #pragma unroll
        for (int t = 0; t < 8; ++t)
            Wh[rr * HID + t * 16 + r] = f2b(acc[t][j]);
    }
}

// per-node softmax + gather-aggregate. One wave per node.
// Quarter-wave per row, 16B/lane -> 4 rows per load instruction,
// 8 independent wide loads in flight, no divergence in the loop.
__global__ __launch_bounds__(256) void k_attn(const int* __restrict__ ctx,
                                              const unsigned short* __restrict__ Wh,
                                              const float* __restrict__ sib,
                                              const float* __restrict__ sjv,
                                              float* __restrict__ out) {
    const int lane = threadIdx.x & 63;
    const long n = (long)blockIdx.x * 4 + (threadIdx.x >> 6);
    const int c = lane & 31;
    const int idx = ctx[n * NCTX + c];
    const int icl = (idx >= 0) ? idx : 0;
    float s;
    if (idx >= 0) {
        s = sib[n] + sjv[icl];
        s = (s >= 0.f) ? s : 0.2f * s;
    } else {
        s = -9e15f;
    }
    float mx = s;
    #pragma unroll
    for (int m = 16; m >= 1; m >>= 1) mx = fmaxf(mx, __shfl_xor(mx, m));
    const float e = __expf(s - mx);
    float sum = e;
    #pragma unroll
    for (int m = 16; m >= 1; m >>= 1) sum += __shfl_xor(sum, m);
    const float at = (idx >= 0) ? e / sum : 0.f;

    const int q  = lane >> 4;    // quarter: which row within the 4-row group
    const int cl = lane & 15;    // 16B column chunk

    float a0 = 0.f, a1 = 0.f, a2 = 0.f, a3 = 0.f, a4 = 0.f, a5 = 0.f, a6 = 0.f, a7 = 0.f;
    #pragma unroll
    for (int it = 0; it < 8; ++it) {
        const int   src = it * 4 + q;
        const float w   = __shfl(at, src);
        const int   ic  = __shfl(icl, src);
        const uint4 pv  = *(const uint4*)(Wh + (long)ic * HID + cl * 8);
        a0 += w * b2f((unsigned short)(pv.x & 0xFFFFu));
        a1 += w * b2f((unsigned short)(pv.x >> 16));
        a2 += w * b2f((unsigned short)(pv.y & 0xFFFFu));
        a3 += w * b2f((unsigned short)(pv.y >> 16));
        a4 += w * b2f((unsigned short)(pv.z & 0xFFFFu));
        a5 += w * b2f((unsigned short)(pv.z >> 16));
        a6 += w * b2f((unsigned short)(pv.w & 0xFFFFu));
        a7 += w * b2f((unsigned short)(pv.w >> 16));
    }
    #pragma unroll
    for (int m = 16; m <= 32; m <<= 1) {
        a0 += __shfl_xor(a0, m); a1 += __shfl_xor(a1, m);
        a2 += __shfl_xor(a2, m); a3 += __shfl_xor(a3, m);
        a4 += __shfl_xor(a4, m); a5 += __shfl_xor(a5, m);
        a6 += __shfl_xor(a6, m); a7 += __shfl_xor(a7, m);
    }
    if (lane < 16) {
        float4* op = (float4*)(out + n * HID + cl * 8);
        op[0] = (float4){a0, a1, a2, a3};
        op[1] = (float4){a4, a5, a6, a7};
    }
}

extern "C" void kernel_launch(void* const* d_in, const int* in_sizes, int n_in,
                              void* d_out, int out_size, void* d_ws, size_t ws_size,
                              hipStream_t stream) {
    const float* h_i = (const float*)d_in[0];
    const int*   ctx = (const int*)d_in[1];
    const float* W_i = (const float*)d_in[2];
    const float* W_j = (const float*)d_in[3];
    const float* a_w = (const float*)d_in[4];
    const float* a_b = (const float*)d_in[5];
    float* out = (float*)d_out;

    char* ws = (char*)d_ws;
    unsigned short* Wh = (unsigned short*)ws;             // N*H bf16 = 7,680,000 B
    float* sib = (float*)(ws + 7680000);                  // N f32
    float* sjv = (float*)(ws + 7800000);                  // N f32
    float* vi  = (float*)(ws + 7920000);                  // 256 f32
    short8* whi = (short8*)(ws + 7921024);                // 64 KB
    short8* wlo = (short8*)(ws + 7986560);                // 64 KB

    k_pack<<<65, 64, 0, stream>>>(W_j, W_i, a_w, whi, wlo, vi);
    k_gemm<<<(NN / 16 + 3) / 4, 256, 0, stream>>>(h_i, whi, wlo, vi, a_w, a_b, Wh, sib, sjv);
    k_attn<<<NN / 4, 256, 0, stream>>>(ctx, Wh, sib, sjv, out);
}

// Round 7
// 52.145 us; speedup vs baseline: 5.8476x; 1.1906x over previous
//
#include <hip/hip_runtime.h>

#define NN   30000
#define NCTX 32
#define FIN  256
#define HID  128

typedef short short8 __attribute__((ext_vector_type(8)));
typedef float f32x4  __attribute__((ext_vector_type(4)));

__device__ __forceinline__ unsigned short f2b(float x) {   // RTNE
    union { float f; unsigned u; } v; v.f = x;
    unsigned r = v.u + 0x7FFFu + ((v.u >> 16) & 1u);
    return (unsigned short)(r >> 16);
}
__device__ __forceinline__ unsigned short f2b_trunc(float x) {
    union { float f; unsigned u; } v; v.f = x;
    return (unsigned short)(v.u >> 16);
}
__device__ __forceinline__ float b2f(unsigned short u) {
    union { unsigned u; float f; } v; v.u = ((unsigned)u) << 16;
    return v.f;
}

// Blocks 0-63: pack W_j into MFMA B-fragment order (split bf16 hi/lo).
// Blocks 64-127: vi[f] = Wi[f,:].aw  -- quarter-wave per feature, coalesced
// float4 loads, shfl reduction (was: 1 wave doing 32768 strided scalar loads
// ~20us serial; now ~2us across 64 waves).
__global__ __launch_bounds__(64) void k_pack(const float* __restrict__ Wj,
                                             const float* __restrict__ Wi,
                                             const float* __restrict__ aw,
                                             short8* __restrict__ whi,
                                             short8* __restrict__ wlo,
                                             float* __restrict__ vi) {
    const int b = blockIdx.x;
    const int l = threadIdx.x;
    if (b >= 64) {
        const int fi = l >> 4;            // 4 features per wave
        const int q  = l & 15;            // 16 lanes per feature
        const int f  = (b - 64) * 4 + fi;
        const float4 w0 = *(const float4*)(Wi + (long)f * HID + q * 8);
        const float4 w1 = *(const float4*)(Wi + (long)f * HID + q * 8 + 4);
        const float4 a0 = *(const float4*)(aw + q * 8);
        const float4 a1 = *(const float4*)(aw + q * 8 + 4);
        float s = w0.x * a0.x + w0.y * a0.y + w0.z * a0.z + w0.w * a0.w
                + w1.x * a1.x + w1.y * a1.y + w1.z * a1.z + w1.w * a1.w;
        s += __shfl_xor(s, 1); s += __shfl_xor(s, 2);
        s += __shfl_xor(s, 4); s += __shfl_xor(s, 8);
        if (q == 0) vi[f] = s;
        return;
    }
    const int s = b >> 3, t = b & 7;
    const int kbase = s * 32 + (l >> 4) * 8;
    const int c = t * 16 + (l & 15);
    short8 hi, lo;
    #pragma unroll
    for (int j = 0; j < 8; ++j) {
        const float w = Wj[(long)(kbase + j) * HID + c];
        const unsigned short h = f2b_trunc(w);
        hi[j] = (short)h;
        lo[j] = (short)f2b(w - b2f(h));
    }
    whi[b * 64 + l] = hi;
    wlo[b * 64 + l] = lo;
}

// Fused: Wh = h_i @ W_j (MFMA, split-bf16), si = h_i.vi + ab, sj = Wh.a_w[128:]
// All 16 weight-fragment loads of an s-iter are issued into registers BEFORE
// the MFMA cluster: one L2 latency per s-iter, not 16.
__global__ __launch_bounds__(256) void k_gemm(const float* __restrict__ hin,
                                              const short8* __restrict__ whi,
                                              const short8* __restrict__ wlo,
                                              const float* __restrict__ vi,
                                              const float* __restrict__ aw,
                                              const float* __restrict__ ab,
                                              unsigned short* __restrict__ Wh,
                                              float* __restrict__ sib,
                                              float* __restrict__ sjv) {
    const int tid  = threadIdx.x;
    const int l    = tid & 63;
    const int wave = blockIdx.x * 4 + (tid >> 6);
    if (wave >= NN / 16) return;
    const long rowbase = (long)wave * 16;
    const int r  = l & 15;    // A row / D col-within-tile
    const int kg = l >> 4;    // k-group

    const float* hrow = hin + (rowbase + r) * FIN + kg * 8;
    const float* vip  = vi + kg * 8;

    f32x4 acc[8];
    #pragma unroll
    for (int t = 0; t < 8; ++t) acc[t] = (f32x4){0.f, 0.f, 0.f, 0.f};
    float si = 0.f;

    #pragma unroll
    for (int s = 0; s < 8; ++s) {
        short8 BH[8], BL[8];
        #pragma unroll
        for (int t = 0; t < 8; ++t) {
            BH[t] = whi[(s * 8 + t) * 64 + l];
            BL[t] = wlo[(s * 8 + t) * 64 + l];
        }
        const float4 ha = *(const float4*)(hrow + s * 32);
        const float4 hb = *(const float4*)(hrow + s * 32 + 4);
        const float4 va = *(const float4*)(vip + s * 32);
        const float4 vb = *(const float4*)(vip + s * 32 + 4);
        const float hv[8] = {ha.x, ha.y, ha.z, ha.w, hb.x, hb.y, hb.z, hb.w};
        const float vv[8] = {va.x, va.y, va.z, va.w, vb.x, vb.y, vb.z, vb.w};
        short8 ahi, alo;
        #pragma unroll
        for (int j = 0; j < 8; ++j) {
            si += hv[j] * vv[j];
            const unsigned short hb16 = f2b_trunc(hv[j]);
            ahi[j] = (short)hb16;
            alo[j] = (short)f2b(hv[j] - b2f(hb16));
        }
        #pragma unroll
        for (int t = 0; t < 8; ++t) {
            acc[t] = __builtin_amdgcn_mfma_f32_16x16x32_bf16(ahi, BH[t], acc[t], 0, 0, 0);
            acc[t] = __builtin_amdgcn_mfma_f32_16x16x32_bf16(alo, BH[t], acc[t], 0, 0, 0);
            acc[t] = __builtin_amdgcn_mfma_f32_16x16x32_bf16(ahi, BL[t], acc[t], 0, 0, 0);
        }
    }

    si += __shfl_xor(si, 16);
    si += __shfl_xor(si, 32);
    if (l < 16) sib[rowbase + l] = si + ab[0];

    float aw2v[8];
    #pragma unroll
    for (int t = 0; t < 8; ++t) aw2v[t] = aw[HID + t * 16 + r];
    #pragma unroll
    for (int j = 0; j < 4; ++j) {
        float p = 0.f;
        #pragma unroll
        for (int t = 0; t < 8; ++t) p += acc[t][j] * aw2v[t];
        p += __shfl_xor(p, 1); p += __shfl_xor(p, 2);
        p += __shfl_xor(p, 4); p += __shfl_xor(p, 8);
        if (r == 0) sjv[rowbase + kg * 4 + j] = p;
    }

    #pragma unroll
    for (int j = 0; j < 4; ++j) {
        const long rr = rowbase + kg * 4 + j;
        #pragma unroll
        for (int t = 0; t < 8; ++t)
            Wh[rr * HID + t * 16 + r] = f2b(acc[t][j]);
    }
}

// per-node softmax + gather-aggregate. One wave per node.
// Quarter-wave per row, 16B/lane -> 4 rows per load instruction,
// 8 independent wide loads in flight, no divergence in the loop.
__global__ __launch_bounds__(256) void k_attn(const int* __restrict__ ctx,
                                              const unsigned short* __restrict__ Wh,
                                              const float* __restrict__ sib,
                                              const float* __restrict__ sjv,
                                              float* __restrict__ out) {
    const int lane = threadIdx.x & 63;
    const long n = (long)blockIdx.x * 4 + (threadIdx.x >> 6);
    const int c = lane & 31;
    const int idx = ctx[n * NCTX + c];
    const int icl = (idx >= 0) ? idx : 0;
    float s;
    if (idx >= 0) {
        s = sib[n] + sjv[icl];
        s = (s >= 0.f) ? s : 0.2f * s;
    } else {
        s = -9e15f;
    }
    float mx = s;
    #pragma unroll
    for (int m = 16; m >= 1; m >>= 1) mx = fmaxf(mx, __shfl_xor(mx, m));
    const float e = __expf(s - mx);
    float sum = e;
    #pragma unroll
    for (int m = 16; m >= 1; m >>= 1) sum += __shfl_xor(sum, m);
    const float at = (idx >= 0) ? e / sum : 0.f;

    const int q  = lane >> 4;
    const int cl = lane & 15;

    float a0 = 0.f, a1 = 0.f, a2 = 0.f, a3 = 0.f, a4 = 0.f, a5 = 0.f, a6 = 0.f, a7 = 0.f;
    #pragma unroll
    for (int it = 0; it < 8; ++it) {
        const int   src = it * 4 + q;
        const float w   = __shfl(at, src);
        const int   ic  = __shfl(icl, src);
        const uint4 pv  = *(const uint4*)(Wh + (long)ic * HID + cl * 8);
        a0 += w * b2f((unsigned short)(pv.x & 0xFFFFu));
        a1 += w * b2f((unsigned short)(pv.x >> 16));
        a2 += w * b2f((unsigned short)(pv.y & 0xFFFFu));
        a3 += w * b2f((unsigned short)(pv.y >> 16));
        a4 += w * b2f((unsigned short)(pv.z & 0xFFFFu));
        a5 += w * b2f((unsigned short)(pv.z >> 16));
        a6 += w * b2f((unsigned short)(pv.w & 0xFFFFu));
        a7 += w * b2f((unsigned short)(pv.w >> 16));
    }
    #pragma unroll
    for (int m = 16; m <= 32; m <<= 1) {
        a0 += __shfl_xor(a0, m); a1 += __shfl_xor(a1, m);
        a2 += __shfl_xor(a2, m); a3 += __shfl_xor(a3, m);
        a4 += __shfl_xor(a4, m); a5 += __shfl_xor(a5, m);
        a6 += __shfl_xor(a6, m); a7 += __shfl_xor(a7, m);
    }
    if (lane < 16) {
        float4* op = (float4*)(out + n * HID + cl * 8);
        op[0] = (float4){a0, a1, a2, a3};
        op[1] = (float4){a4, a5, a6, a7};
    }
}

extern "C" void kernel_launch(void* const* d_in, const int* in_sizes, int n_in,
                              void* d_out, int out_size, void* d_ws, size_t ws_size,
                              hipStream_t stream) {
    const float* h_i = (const float*)d_in[0];
    const int*   ctx = (const int*)d_in[1];
    const float* W_i = (const float*)d_in[2];
    const float* W_j = (const float*)d_in[3];
    const float* a_w = (const float*)d_in[4];
    const float* a_b = (const float*)d_in[5];
    float* out = (float*)d_out;

    char* ws = (char*)d_ws;
    unsigned short* Wh = (unsigned short*)ws;             // N*H bf16 = 7,680,000 B
    float* sib = (float*)(ws + 7680000);                  // N f32
    float* sjv = (float*)(ws + 7800000);                  // N f32
    float* vi  = (float*)(ws + 7920000);                  // 256 f32
    short8* whi = (short8*)(ws + 7921024);                // 64 KB
    short8* wlo = (short8*)(ws + 7986560);                // 64 KB

    k_pack<<<128, 64, 0, stream>>>(W_j, W_i, a_w, whi, wlo, vi);
    k_gemm<<<(NN / 16 + 3) / 4, 256, 0, stream>>>(h_i, whi, wlo, vi, a_w, a_b, Wh, sib, sjv);
    k_attn<<<NN / 4, 256, 0, stream>>>(ctx, Wh, sib, sjv, out);
}